// Round 7
// baseline (122.833 us; speedup 1.0000x reference)
//
#include <hip/hip_runtime.h>

typedef __attribute__((ext_vector_type(8))) __bf16 bf16x8;
typedef __attribute__((ext_vector_type(4))) __bf16 bf16x4;
typedef __attribute__((ext_vector_type(4))) float f32x4;

// barrier WITHOUT vmcnt drain: LDS ops must land, global loads stay in flight
#define LGKM_BAR() do { asm volatile("s_waitcnt lgkmcnt(0)" ::: "memory"); \
                        __builtin_amdgcn_s_barrier(); } while (0)

namespace {
constexpr int N_ = 64, C_ = 512, P_ = 900, K_ = 64;
constexpr int PP = 960;                               // padded P
constexpr size_t TOT_X = (size_t)N_ * C_ * P_;        // 29,491,200 floats (118 MB)
constexpr size_t AT_BYTES = (size_t)N_ * K_ * PP * 2;         // bf16 a' [n][k][960]
constexpr size_t ASUM_OFF = AT_BYTES;                         // f32 [n][k]
constexpr size_t WB_OFF   = ASUM_OFF + (size_t)N_ * K_ * 4;   // bf16 w [k][c]
constexpr size_t XT_OFF   = 8388608;                          // bf16 xt [n][960][512]
}

// --- w f32 [K][C] -> bf16 [K][C]; also zero asum
__global__ __launch_bounds__(256) void k_prep_w(const float* __restrict__ w,
                                                __bf16* __restrict__ wb,
                                                float* __restrict__ asum) {
  const int t = blockIdx.x * 256 + threadIdx.x;
  const int i = t * 4;
  if (i < K_ * C_) {
    float4 v = *reinterpret_cast<const float4*>(w + i);
    wb[i]   = (__bf16)v.x; wb[i+1] = (__bf16)v.y;
    wb[i+2] = (__bf16)v.z; wb[i+3] = (__bf16)v.w;
  }
  if (t < N_ * K_) asum[t] = 0.f;
}

// --- transpose+convert: x f32 [n][c][900] -> xt bf16 [n][960][512] (pad rows = 0)
__global__ __launch_bounds__(256) void k_convert(const float* __restrict__ x,
                                                 __bf16* __restrict__ xt) {
  __shared__ float T[64][65];
  const int n = blockIdx.z, c0 = blockIdx.y * 64, p0 = blockIdx.x * 64;
  const int tid = threadIdx.x;
  const int cr = tid >> 4, pq = (tid & 15) * 4;
  #pragma unroll
  for (int i = 0; i < 4; ++i) {
    const int c = cr + i * 16;
    float4 v = make_float4(0.f, 0.f, 0.f, 0.f);
    if (p0 + pq < P_)   // P_%4==0: in-bounds float4 whenever start < P_
      v = *reinterpret_cast<const float4*>(
          x + ((size_t)n * C_ + c0 + c) * P_ + p0 + pq);
    *reinterpret_cast<float4*>(&T[c][pq]) = v;
  }
  __syncthreads();
  const int pr = tid >> 2, cs = (tid & 3) * 16;
  bf16x8 o0, o1;
  #pragma unroll
  for (int j = 0; j < 8; ++j) o0[j] = (__bf16)T[cs + j][pr];
  #pragma unroll
  for (int j = 0; j < 8; ++j) o1[j] = (__bf16)T[cs + 8 + j][pr];
  __bf16* dst = xt + ((size_t)n * PP + p0 + pr) * C_ + c0 + cs;
  *reinterpret_cast<bf16x8*>(dst)     = o0;
  *reinterpret_cast<bf16x8*>(dst + 8) = o1;
}

// --- phase 1 (no LDS, no barriers): per wave: 16 p-rows x all 64 k.
//     B-frags straight from xt; A-frags from L2-hot wb; ssq from bf16 frags;
//     softmax fully in-wave via shfl_xor.
__global__ __launch_bounds__(256) void k_phase1(const __bf16* __restrict__ xt,
                                                const __bf16* __restrict__ wb,
                                                __bf16* __restrict__ at,
                                                float* __restrict__ asum) {
  const int n   = blockIdx.y;
  const int tid = threadIdx.x;
  const int w   = tid >> 6, l = tid & 63;
  const int l15 = l & 15,  lh = l >> 4;
  const int p   = blockIdx.x * 64 + w * 16 + l15;     // this lane's p (col)
  const __bf16* xrow  = xt + ((size_t)n * PP + p) * C_ + lh * 8;
  const __bf16* wbase = wb + (size_t)l15 * C_ + lh * 8;

  f32x4 acc[4] = {};                  // m: k = 16m + lh*4 + r
  float sq = 0.f;
  #pragma unroll
  for (int s = 0; s < 16; ++s) {
    bf16x8 b = *reinterpret_cast<const bf16x8*>(xrow + s * 32);
    #pragma unroll
    for (int j = 0; j < 8; ++j) { const float f = (float)b[j]; sq = fmaf(f, f, sq); }
    #pragma unroll
    for (int m = 0; m < 4; ++m) {
      bf16x8 a = *reinterpret_cast<const bf16x8*>(wbase + (size_t)m * 16 * C_ + s * 32);
      acc[m] = __builtin_amdgcn_mfma_f32_16x16x32_bf16(a, b, acc[m], 0, 0, 0);
    }
  }
  // full ssq for this p: reduce partials across lh groups (same l15)
  sq += __shfl_xor(sq, 16, 64);
  sq += __shfl_xor(sq, 32, 64);
  const float invn = 1.f / fmaxf(sqrtf(sq), 1e-12f);
  const bool  valid = p < P_;

  float ps = 0.f;
  #pragma unroll
  for (int m = 0; m < 4; ++m)
    #pragma unroll
    for (int r = 0; r < 4; ++r) {
      acc[m][r] = __expf(acc[m][r] * invn);   // maxless: |logit| <= ~0.5
      ps += acc[m][r];
    }
  ps += __shfl_xor(ps, 16, 64);
  ps += __shfl_xor(ps, 32, 64);
  const float invs = 1.f / ps;
  const float sc   = invs * invn;

  #pragma unroll
  for (int m = 0; m < 4; ++m)
    #pragma unroll
    for (int r = 0; r < 4; ++r) {
      const int k = 16 * m + lh * 4 + r;
      at[((size_t)n * K_ + k) * PP + p] =
          valid ? (__bf16)(acc[m][r] * sc) : (__bf16)0.f;
    }
  #pragma unroll
  for (int m = 0; m < 4; ++m)
    #pragma unroll
    for (int r = 0; r < 4; ++r) {
      float v = valid ? acc[m][r] * invs : 0.f;
      v += __shfl_xor(v, 1, 64); v += __shfl_xor(v, 2, 64);
      v += __shfl_xor(v, 4, 64); v += __shfl_xor(v, 8, 64);
      if (l15 == 0)
        unsafeAtomicAdd(asum + n * K_ + 16 * m + lh * 4 + r, v);
    }
}

// --- phase 2 (unchanged from R6): vlad[k][c] = sum_p a'[k][p]*x[c][p] - asum[k]*cent[k][c]
__global__ __launch_bounds__(256) void k_phase2(const float* __restrict__ x,
                                                const __bf16* __restrict__ at,
                                                const float* __restrict__ asum,
                                                const float* __restrict__ cent,
                                                float* __restrict__ out) {
  __shared__ __bf16 Al[2][64][40];   // [buf][k][p32+pad]
  __shared__ __bf16 Xl[2][64][40];   // [buf][c][p32+pad]
  const int n   = blockIdx.y;
  const int c0  = blockIdx.x * 64;
  const int tid = threadIdx.x;
  const int w   = tid >> 6, l = tid & 63;
  const int l15 = l & 15,  lh = l >> 4;

  const int ak  = tid >> 2, ach = tid & 3;      // A staging: k, p-octet
  const int xc  = tid >> 3, xch = tid & 7;      // X staging (x2): c, p-quad
  const size_t abase  = ((size_t)n * K_ + ak) * PP + ach * 8;
  const size_t xbase0 = ((size_t)n * C_ + c0 + xc) * P_ + xch * 4;
  const size_t xbase1 = ((size_t)n * C_ + c0 + xc + 32) * P_ + xch * 4;

  f32x4 acc[4] = {};                 // frag m: k=16m+lh*4+r, c=c0+16w+l15
  bf16x8 na; float4 v0, v1;

  auto LOAD = [&](int s) {
    na = *reinterpret_cast<const bf16x8*>(at + abase + s * 32);
    size_t o0 = xbase0 + s * 32; if (o0 > TOT_X - 4) o0 = TOT_X - 4;
    size_t o1 = xbase1 + s * 32; if (o1 > TOT_X - 4) o1 = TOT_X - 4;
    v0 = *reinterpret_cast<const float4*>(x + o0);
    v1 = *reinterpret_cast<const float4*>(x + o1);
  };
  auto STORE = [&](int b) {
    *reinterpret_cast<bf16x8*>(&Al[b][ak][ach * 8]) = na;
    bf16x4 p0 = { (__bf16)v0.x, (__bf16)v0.y, (__bf16)v0.z, (__bf16)v0.w };
    bf16x4 p1 = { (__bf16)v1.x, (__bf16)v1.y, (__bf16)v1.z, (__bf16)v1.w };
    *reinterpret_cast<bf16x4*>(&Xl[b][xc][xch * 4])      = p0;
    *reinterpret_cast<bf16x4*>(&Xl[b][xc + 32][xch * 4]) = p1;
  };

  LOAD(0); STORE(0);
  LGKM_BAR();

  #pragma unroll 2
  for (int s = 0; s < 29; ++s) {     // K-dim p: 29 steps of 32 (at pad = 0)
    if (s < 28) LOAD(s + 1);
    bf16x8 b = *reinterpret_cast<const bf16x8*>(&Xl[s & 1][16 * w + l15][lh * 8]);
    #pragma unroll
    for (int m = 0; m < 4; ++m) {
      bf16x8 a = *reinterpret_cast<const bf16x8*>(&Al[s & 1][16 * m + l15][lh * 8]);
      acc[m] = __builtin_amdgcn_mfma_f32_16x16x32_bf16(a, b, acc[m], 0, 0, 0);
    }
    if (s < 28) STORE((s + 1) & 1);
    LGKM_BAR();
  }

  const int c = c0 + 16 * w + l15;
  #pragma unroll
  for (int m = 0; m < 4; ++m) {
    #pragma unroll
    for (int r = 0; r < 4; ++r) {
      const int k = 16 * m + lh * 4 + r;
      out[((size_t)n * K_ + k) * C_ + c] =
          acc[m][r] - asum[n * K_ + k] * cent[(size_t)k * C_ + c];
    }
  }
}

extern "C" void kernel_launch(void* const* d_in, const int* in_sizes, int n_in,
                              void* d_out, int out_size, void* d_ws, size_t ws_size,
                              hipStream_t stream) {
  const float* x    = (const float*)d_in[0];
  const float* w    = (const float*)d_in[1];
  const float* cent = (const float*)d_in[2];
  float* out = (float*)d_out;
  char* wsb  = (char*)d_ws;
  __bf16* at   = (__bf16*)wsb;
  float*  asum = (float*)(wsb + ASUM_OFF);
  __bf16* wb   = (__bf16*)(wsb + WB_OFF);
  __bf16* xt   = (__bf16*)(wsb + XT_OFF);

  k_prep_w<<<dim3(32), dim3(256), 0, stream>>>(w, wb, asum);
  k_convert<<<dim3(15, 8, 64), dim3(256), 0, stream>>>(x, xt);
  k_phase1<<<dim3(15, 64), dim3(256), 0, stream>>>(xt, wb, at, asum);
  k_phase2<<<dim3(8, 64), dim3(256), 0, stream>>>(x, at, asum, cent, out);
}

// Round 8
// 83.541 us; speedup vs baseline: 1.4703x; 1.4703x over previous
//
#include <hip/hip_runtime.h>

typedef __attribute__((ext_vector_type(8))) __bf16 bf16x8;
typedef __attribute__((ext_vector_type(4))) __bf16 bf16x4;
typedef __attribute__((ext_vector_type(4))) float f32x4;

// barrier WITHOUT vmcnt drain: LDS ops must land, global loads stay in flight
#define LGKM_BAR() do { asm volatile("s_waitcnt lgkmcnt(0)" ::: "memory"); \
                        __builtin_amdgcn_s_barrier(); } while (0)

namespace {
constexpr int N_ = 64, C_ = 512, P_ = 900, K_ = 64;
constexpr int PP = 960;                               // padded P for at
constexpr size_t TOT_X = (size_t)N_ * C_ * P_;        // 117,964,800 floats
constexpr size_t AT_BYTES = (size_t)N_ * K_ * PP * 2;         // bf16 a' [n][k][960]
constexpr size_t ASUM_OFF = AT_BYTES;                         // f32 [n][k]
constexpr size_t WB_OFF   = ASUM_OFF + (size_t)N_ * K_ * 4;   // bf16 w [k][c]
}

// --- w f32 [K][C] -> bf16 [K][C]; also zero asum
__global__ __launch_bounds__(256) void k_prep_w(const float* __restrict__ w,
                                                __bf16* __restrict__ wb,
                                                float* __restrict__ asum) {
  const int t = blockIdx.x * 256 + threadIdx.x;
  const int i = t * 4;
  if (i < K_ * C_) {
    float4 v = *reinterpret_cast<const float4*>(w + i);
    wb[i]   = (__bf16)v.x; wb[i+1] = (__bf16)v.y;
    wb[i+2] = (__bf16)v.z; wb[i+3] = (__bf16)v.w;
  }
  if (t < N_ * K_) asum[t] = 0.f;
}

// --- phase 1: NO LDS, NO barriers. Wave owns 16 p-rows x all 64 k.
//     Each lane gathers its own B-fragment (8 strided dwords) straight from x;
//     ssq fused on the f32 values; in-wave softmax; writes bf16 a' + asum.
__global__ __launch_bounds__(256) void k_phase1(const float* __restrict__ x,
                                                const __bf16* __restrict__ wb,
                                                __bf16* __restrict__ at,
                                                float* __restrict__ asum) {
  const int n   = blockIdx.y;
  const int tid = threadIdx.x;
  const int w   = tid >> 6, l = tid & 63;
  const int l15 = l & 15,  lh = l >> 4;
  const int p   = blockIdx.x * 64 + w * 16 + l15;   // this lane's p (D col)
  const int pc  = p < P_ ? p : P_ - 1;              // clamp: garbage discarded
  // lane's gather base: c = lh*8 + j + 32*s, own p
  const float*  xp    = x + (size_t)n * C_ * P_ + (size_t)lh * 8 * P_ + pc;
  const __bf16* wbase = wb + (size_t)l15 * C_ + lh * 8;

  f32x4 acc[4] = {};                  // m: k = 16m + lh*4 + r
  float sq = 0.f;
  #pragma unroll
  for (int s = 0; s < 16; ++s) {
    float g[8];
    #pragma unroll
    for (int j = 0; j < 8; ++j)
      g[j] = xp[(size_t)(s * 32 + j) * P_];
    bf16x8 b;
    #pragma unroll
    for (int j = 0; j < 8; ++j) { sq = fmaf(g[j], g[j], sq); b[j] = (__bf16)g[j]; }
    #pragma unroll
    for (int m = 0; m < 4; ++m) {
      bf16x8 a = *reinterpret_cast<const bf16x8*>(wbase + (size_t)m * 16 * C_ + s * 32);
      acc[m] = __builtin_amdgcn_mfma_f32_16x16x32_bf16(a, b, acc[m], 0, 0, 0);
    }
  }
  // full ssq for this p: reduce partials across the 4 lh groups (same l15)
  sq += __shfl_xor(sq, 16, 64);
  sq += __shfl_xor(sq, 32, 64);
  const float invn = 1.f / fmaxf(sqrtf(sq), 1e-12f);
  const bool  valid = p < P_;

  float ps = 0.f;
  #pragma unroll
  for (int m = 0; m < 4; ++m)
    #pragma unroll
    for (int r = 0; r < 4; ++r) {
      acc[m][r] = __expf(acc[m][r] * invn);   // maxless: |logit| <= ~0.5
      ps += acc[m][r];
    }
  ps += __shfl_xor(ps, 16, 64);
  ps += __shfl_xor(ps, 32, 64);
  const float invs = 1.f / ps;
  const float sc   = invs * invn;

  #pragma unroll
  for (int m = 0; m < 4; ++m)
    #pragma unroll
    for (int r = 0; r < 4; ++r) {
      const int k = 16 * m + lh * 4 + r;
      at[((size_t)n * K_ + k) * PP + p] =
          valid ? (__bf16)(acc[m][r] * sc) : (__bf16)0.f;
    }
  #pragma unroll
  for (int m = 0; m < 4; ++m)
    #pragma unroll
    for (int r = 0; r < 4; ++r) {
      float v = valid ? acc[m][r] * invs : 0.f;
      v += __shfl_xor(v, 1, 64); v += __shfl_xor(v, 2, 64);
      v += __shfl_xor(v, 4, 64); v += __shfl_xor(v, 8, 64);
      if (l15 == 0)
        unsafeAtomicAdd(asum + n * K_ + 16 * m + lh * 4 + r, v);
    }
}

// --- phase 2 (unchanged from R6): vlad[k][c] = sum_p a'[k][p]*x[c][p] - asum[k]*cent[k][c]
__global__ __launch_bounds__(256) void k_phase2(const float* __restrict__ x,
                                                const __bf16* __restrict__ at,
                                                const float* __restrict__ asum,
                                                const float* __restrict__ cent,
                                                float* __restrict__ out) {
  __shared__ __bf16 Al[2][64][40];   // [buf][k][p32+pad]
  __shared__ __bf16 Xl[2][64][40];   // [buf][c][p32+pad]
  const int n   = blockIdx.y;
  const int c0  = blockIdx.x * 64;
  const int tid = threadIdx.x;
  const int w   = tid >> 6, l = tid & 63;
  const int l15 = l & 15,  lh = l >> 4;

  const int ak  = tid >> 2, ach = tid & 3;      // A staging: k, p-octet
  const int xc  = tid >> 3, xch = tid & 7;      // X staging (x2): c, p-quad
  const size_t abase  = ((size_t)n * K_ + ak) * PP + ach * 8;
  const size_t xbase0 = ((size_t)n * C_ + c0 + xc) * P_ + xch * 4;
  const size_t xbase1 = ((size_t)n * C_ + c0 + xc + 32) * P_ + xch * 4;

  f32x4 acc[4] = {};                 // frag m: k=16m+lh*4+r, c=c0+16w+l15
  bf16x8 na; float4 v0, v1;

  auto LOAD = [&](int s) {
    na = *reinterpret_cast<const bf16x8*>(at + abase + s * 32);
    size_t o0 = xbase0 + s * 32; if (o0 > TOT_X - 4) o0 = TOT_X - 4;
    size_t o1 = xbase1 + s * 32; if (o1 > TOT_X - 4) o1 = TOT_X - 4;
    v0 = *reinterpret_cast<const float4*>(x + o0);
    v1 = *reinterpret_cast<const float4*>(x + o1);
  };
  auto STORE = [&](int b) {
    *reinterpret_cast<bf16x8*>(&Al[b][ak][ach * 8]) = na;
    bf16x4 p0 = { (__bf16)v0.x, (__bf16)v0.y, (__bf16)v0.z, (__bf16)v0.w };
    bf16x4 p1 = { (__bf16)v1.x, (__bf16)v1.y, (__bf16)v1.z, (__bf16)v1.w };
    *reinterpret_cast<bf16x4*>(&Xl[b][xc][xch * 4])      = p0;
    *reinterpret_cast<bf16x4*>(&Xl[b][xc + 32][xch * 4]) = p1;
  };

  LOAD(0); STORE(0);
  LGKM_BAR();

  #pragma unroll 2
  for (int s = 0; s < 29; ++s) {     // K-dim p: 29 steps of 32 (at pad = 0)
    if (s < 28) LOAD(s + 1);
    bf16x8 b = *reinterpret_cast<const bf16x8*>(&Xl[s & 1][16 * w + l15][lh * 8]);
    #pragma unroll
    for (int m = 0; m < 4; ++m) {
      bf16x8 a = *reinterpret_cast<const bf16x8*>(&Al[s & 1][16 * m + l15][lh * 8]);
      acc[m] = __builtin_amdgcn_mfma_f32_16x16x32_bf16(a, b, acc[m], 0, 0, 0);
    }
    if (s < 28) STORE((s + 1) & 1);
    LGKM_BAR();
  }

  const int c = c0 + 16 * w + l15;
  #pragma unroll
  for (int m = 0; m < 4; ++m) {
    #pragma unroll
    for (int r = 0; r < 4; ++r) {
      const int k = 16 * m + lh * 4 + r;
      out[((size_t)n * K_ + k) * C_ + c] =
          acc[m][r] - asum[n * K_ + k] * cent[(size_t)k * C_ + c];
    }
  }
}

extern "C" void kernel_launch(void* const* d_in, const int* in_sizes, int n_in,
                              void* d_out, int out_size, void* d_ws, size_t ws_size,
                              hipStream_t stream) {
  const float* x    = (const float*)d_in[0];
  const float* w    = (const float*)d_in[1];
  const float* cent = (const float*)d_in[2];
  float* out = (float*)d_out;
  char* wsb  = (char*)d_ws;
  __bf16* at   = (__bf16*)wsb;
  float*  asum = (float*)(wsb + ASUM_OFF);
  __bf16* wb   = (__bf16*)(wsb + WB_OFF);

  k_prep_w<<<dim3(32), dim3(256), 0, stream>>>(w, wb, asum);
  k_phase1<<<dim3(15, 64), dim3(256), 0, stream>>>(x, wb, at, asum);
  k_phase2<<<dim3(8, 64), dim3(256), 0, stream>>>(x, at, asum, cent, out);
}

// Round 9
// 69.820 us; speedup vs baseline: 1.7593x; 1.1965x over previous
//
#include <hip/hip_runtime.h>

typedef __attribute__((ext_vector_type(8))) __bf16 bf16x8;
typedef __attribute__((ext_vector_type(4))) __bf16 bf16x4;
typedef __attribute__((ext_vector_type(4))) float f32x4;

// barrier WITHOUT vmcnt drain: LDS ops must land, global loads stay in flight
#define LGKM_BAR() do { asm volatile("s_waitcnt lgkmcnt(0)" ::: "memory"); \
                        __builtin_amdgcn_s_barrier(); } while (0)

namespace {
constexpr int N_ = 64, C_ = 512, P_ = 900, K_ = 64;
constexpr int PP = 960;                               // padded P for at
constexpr size_t TOT_X = (size_t)N_ * C_ * P_;        // 117,964,800 floats
constexpr size_t AT_BYTES = (size_t)N_ * K_ * PP * 2;         // bf16 a' [n][k][960]
constexpr size_t ASUM_OFF = AT_BYTES;                         // f32 [n][k]
constexpr size_t WBR_OFF  = ASUM_OFF + (size_t)N_ * K_ * 4;   // bf16 wbr [c/8][k][c%8]
}

// --- prep: wbr[oct][k][j] = bf16(w[k][oct*8+j]) (A-frag-ready layout); zero asum.
__global__ __launch_bounds__(256) void k_prep_w(const float* __restrict__ w,
                                                __bf16* __restrict__ wbr,
                                                float* __restrict__ asum) {
  const int T = blockIdx.x * 256 + threadIdx.x;      // 0..4095
  const int k = T >> 6, oct = T & 63;
  const float4 a = *reinterpret_cast<const float4*>(w + (size_t)k * C_ + oct * 8);
  const float4 b = *reinterpret_cast<const float4*>(w + (size_t)k * C_ + oct * 8 + 4);
  bf16x8 o = { (__bf16)a.x, (__bf16)a.y, (__bf16)a.z, (__bf16)a.w,
               (__bf16)b.x, (__bf16)b.y, (__bf16)b.z, (__bf16)b.w };
  *reinterpret_cast<bf16x8*>(wbr + ((size_t)oct * K_ + k) * 8) = o;
  asum[T] = 0.f;
}

// --- phase 1: barrier-free MFMA loop. 512 thr / 8 waves; wave = 16 p x all 64 k.
//     A-frags from LDS (staged once, lgkmcnt); x gathered per-lane into a 6-slot
//     register ring (vmcnt only) -> ~40 loads permanently in flight per wave.
__global__ __launch_bounds__(512) void k_phase1(const float* __restrict__ x,
                                                const __bf16* __restrict__ wbr,
                                                __bf16* __restrict__ at,
                                                float* __restrict__ asum) {
  __shared__ bf16x8 Wl[4096];        // 64 KB: [oct][k] -> one b128 = A-frag slice
  const int n   = blockIdx.y;
  const int tid = threadIdx.x;
  const int w   = tid >> 6, l = tid & 63;
  const int l15 = l & 15,  lh = l >> 4;
  const int p   = blockIdx.x * 128 + w * 16 + l15;  // this lane's p (D col)
  const int pc  = p < P_ ? p : P_ - 1;              // clamped for reads
  const float* xp = x + (size_t)n * C_ * P_ + (size_t)lh * 8 * P_ + pc;

  // one-time stage wbr -> LDS (reg round-trip; loads all issue before stores)
  bf16x8 tmp[8];
  #pragma unroll
  for (int it = 0; it < 8; ++it)
    tmp[it] = *reinterpret_cast<const bf16x8*>(wbr + (size_t)(it * 512 + tid) * 8);

  // ring prologue: slots 0..5 (newer than stage loads -> stage wait won't drain)
  float g[6][8];
  #pragma unroll
  for (int b = 0; b < 6; ++b)
    #pragma unroll
    for (int j = 0; j < 8; ++j)
      g[b][j] = xp[(size_t)(b * 32 + j) * P_];

  #pragma unroll
  for (int it = 0; it < 8; ++it)
    Wl[it * 512 + tid] = tmp[it];
  LGKM_BAR();

  f32x4 acc[4] = {};                  // m: k = 16m + lh*4 + r
  float sq = 0.f;
  #pragma unroll
  for (int s = 0; s < 16; ++s) {
    // consume slot s%6 (convert + ssq)
    bf16x8 b;
    #pragma unroll
    for (int j = 0; j < 8; ++j) {
      const float v = g[s % 6][j];
      sq = fmaf(v, v, sq); b[j] = (__bf16)v;
    }
    // refill same slot with step s+6
    if (s + 6 < 16) {
      #pragma unroll
      for (int j = 0; j < 8; ++j)
        g[s % 6][j] = xp[(size_t)((s + 6) * 32 + j) * P_];
    }
    #pragma unroll
    for (int m = 0; m < 4; ++m) {
      bf16x8 a = Wl[(s * 4 + lh) * 64 + 16 * m + l15];
      acc[m] = __builtin_amdgcn_mfma_f32_16x16x32_bf16(a, b, acc[m], 0, 0, 0);
    }
  }

  // full ssq for this p: reduce partials across the 4 lh groups (same l15)
  sq += __shfl_xor(sq, 16, 64);
  sq += __shfl_xor(sq, 32, 64);
  const float invn = 1.f / fmaxf(sqrtf(sq), 1e-12f);
  const bool  valid = p < P_;

  float ps = 0.f;
  #pragma unroll
  for (int m = 0; m < 4; ++m)
    #pragma unroll
    for (int r = 0; r < 4; ++r) {
      acc[m][r] = __expf(acc[m][r] * invn);   // maxless: |logit| <= ~0.5
      ps += acc[m][r];
    }
  ps += __shfl_xor(ps, 16, 64);
  ps += __shfl_xor(ps, 32, 64);
  const float invs = 1.f / ps;
  const float sc   = invs * invn;

  if (p < PP) {                        // at has rows only up to PP
    #pragma unroll
    for (int m = 0; m < 4; ++m)
      #pragma unroll
      for (int r = 0; r < 4; ++r) {
        const int k = 16 * m + lh * 4 + r;
        at[((size_t)n * K_ + k) * PP + p] =
            valid ? (__bf16)(acc[m][r] * sc) : (__bf16)0.f;
      }
  }
  #pragma unroll
  for (int m = 0; m < 4; ++m)
    #pragma unroll
    for (int r = 0; r < 4; ++r) {
      float v = valid ? acc[m][r] * invs : 0.f;
      v += __shfl_xor(v, 1, 64); v += __shfl_xor(v, 2, 64);
      v += __shfl_xor(v, 4, 64); v += __shfl_xor(v, 8, 64);
      if (l15 == 0)
        unsafeAtomicAdd(asum + n * K_ + 16 * m + lh * 4 + r, v);
    }
}

// --- phase 2 (unchanged): vlad[k][c] = sum_p a'[k][p]*x[c][p] - asum[k]*cent[k][c]
__global__ __launch_bounds__(256) void k_phase2(const float* __restrict__ x,
                                                const __bf16* __restrict__ at,
                                                const float* __restrict__ asum,
                                                const float* __restrict__ cent,
                                                float* __restrict__ out) {
  __shared__ __bf16 Al[2][64][40];   // [buf][k][p32+pad]
  __shared__ __bf16 Xl[2][64][40];   // [buf][c][p32+pad]
  const int n   = blockIdx.y;
  const int c0  = blockIdx.x * 64;
  const int tid = threadIdx.x;
  const int w   = tid >> 6, l = tid & 63;
  const int l15 = l & 15,  lh = l >> 4;

  const int ak  = tid >> 2, ach = tid & 3;      // A staging: k, p-octet
  const int xc  = tid >> 3, xch = tid & 7;      // X staging (x2): c, p-quad
  const size_t abase  = ((size_t)n * K_ + ak) * PP + ach * 8;
  const size_t xbase0 = ((size_t)n * C_ + c0 + xc) * P_ + xch * 4;
  const size_t xbase1 = ((size_t)n * C_ + c0 + xc + 32) * P_ + xch * 4;

  f32x4 acc[4] = {};                 // frag m: k=16m+lh*4+r, c=c0+16w+l15
  bf16x8 na; float4 v0, v1;

  auto LOAD = [&](int s) {
    na = *reinterpret_cast<const bf16x8*>(at + abase + s * 32);
    size_t o0 = xbase0 + s * 32; if (o0 > TOT_X - 4) o0 = TOT_X - 4;
    size_t o1 = xbase1 + s * 32; if (o1 > TOT_X - 4) o1 = TOT_X - 4;
    v0 = *reinterpret_cast<const float4*>(x + o0);
    v1 = *reinterpret_cast<const float4*>(x + o1);
  };
  auto STORE = [&](int b) {
    *reinterpret_cast<bf16x8*>(&Al[b][ak][ach * 8]) = na;
    bf16x4 p0 = { (__bf16)v0.x, (__bf16)v0.y, (__bf16)v0.z, (__bf16)v0.w };
    bf16x4 p1 = { (__bf16)v1.x, (__bf16)v1.y, (__bf16)v1.z, (__bf16)v1.w };
    *reinterpret_cast<bf16x4*>(&Xl[b][xc][xch * 4])      = p0;
    *reinterpret_cast<bf16x4*>(&Xl[b][xc + 32][xch * 4]) = p1;
  };

  LOAD(0); STORE(0);
  LGKM_BAR();

  #pragma unroll 2
  for (int s = 0; s < 29; ++s) {     // K-dim p: 29 steps of 32 (at pad = 0)
    if (s < 28) LOAD(s + 1);
    bf16x8 b = *reinterpret_cast<const bf16x8*>(&Xl[s & 1][16 * w + l15][lh * 8]);
    #pragma unroll
    for (int m = 0; m < 4; ++m) {
      bf16x8 a = *reinterpret_cast<const bf16x8*>(&Al[s & 1][16 * m + l15][lh * 8]);
      acc[m] = __builtin_amdgcn_mfma_f32_16x16x32_bf16(a, b, acc[m], 0, 0, 0);
    }
    if (s < 28) STORE((s + 1) & 1);
    LGKM_BAR();
  }

  const int c = c0 + 16 * w + l15;
  #pragma unroll
  for (int m = 0; m < 4; ++m) {
    #pragma unroll
    for (int r = 0; r < 4; ++r) {
      const int k = 16 * m + lh * 4 + r;
      out[((size_t)n * K_ + k) * C_ + c] =
          acc[m][r] - asum[n * K_ + k] * cent[(size_t)k * C_ + c];
    }
  }
}

extern "C" void kernel_launch(void* const* d_in, const int* in_sizes, int n_in,
                              void* d_out, int out_size, void* d_ws, size_t ws_size,
                              hipStream_t stream) {
  const float* x    = (const float*)d_in[0];
  const float* w    = (const float*)d_in[1];
  const float* cent = (const float*)d_in[2];
  float* out = (float*)d_out;
  char* wsb  = (char*)d_ws;
  __bf16* at   = (__bf16*)wsb;
  float*  asum = (float*)(wsb + ASUM_OFF);
  __bf16* wbr  = (__bf16*)(wsb + WBR_OFF);

  k_prep_w<<<dim3(16), dim3(256), 0, stream>>>(w, wbr, asum);
  k_phase1<<<dim3(8, 64), dim3(512), 0, stream>>>(x, wbr, at, asum);
  k_phase2<<<dim3(8, 64), dim3(256), 0, stream>>>(x, at, asum, cent, out);
}